// Round 3
// baseline (2194.714 us; speedup 1.0000x reference)
//
#include <hip/hip_runtime.h>
#include <hip/hip_bf16.h>

// SignalDecoder: 2-layer bidirectional LSTM, 52 steps, B=1024, HID=256.
// Round 6: persistent kernel, FENCE-FREE coherence.
//   R5 post-mortem: per-stage exec is only ~4us; ~10us/stage is dependent-launch
//   overhead (104 launches ~= 1ms). R4 post-mortem: persistent failed because
//   agent __threadfence = buffer_inv nukes the XCD L2 64x/step/XCD.
//   New: NO fences. Cross-block data goes through L3 via device-scope (sc1)
//   accesses that bypass L2; barrier = vmcnt(0) drain + relaxed agent atomic.
//   - h0 (ping-pong buffer, rewritten every 2 steps): sc1 both sides (atomic
//     8B loads / global_store_short sc1).
//   - h1 == output y: stored ONCE to out[] f32 with sc1 (never L2-dirty, never
//     rewritten) -> readers use PLAIN CACHED loads (first touch fetches fresh
//     from L3, then XCD L2 dedups across the 32-block cluster). f2bf on read
//     reproduces the old bf16 values bit-exactly.
//   - weights: layer-0 slice LDS-resident (96KB, loaded once); layer-1 slice
//     in regs/L2. C-state in registers for all 52 steps. Zero L2 invalidates.
// Cluster = 32 blocks sharing a 128-row tile (mb = bx&7, same XCD under %8
// dispatch - perf only; correctness is sc1+L3). 256 blocks, 1/CU, co-resident.

#define NSTEPS 52

typedef __attribute__((ext_vector_type(8))) short bf16x8;
typedef __attribute__((ext_vector_type(4))) float f32x4;
typedef __attribute__((ext_vector_type(4))) unsigned int u32x4;

__device__ __forceinline__ unsigned short f2bf(float f) {
  union { float f; unsigned int u; } v; v.f = f;
  unsigned int r = v.u + 0x7fffu + ((v.u >> 16) & 1u);  // RNE
  return (unsigned short)(r >> 16);
}

__device__ __forceinline__ float sigm(float x) { return 1.f / (1.f + __expf(-x)); }
__device__ __forceinline__ float tanh_f(float x) { return 2.f / (1.f + __expf(-2.f * x)) - 1.f; }

__device__ __forceinline__ void async_ld16(const unsigned short* g, unsigned short* l) {
  __builtin_amdgcn_global_load_lds(
      (const __attribute__((address_space(1))) unsigned int*)g,
      (__attribute__((address_space(3))) unsigned int*)l, 16, 0, 0);
}

// Device-scope (L2-bypassing) 16B load as 2x8B relaxed agent atomics.
__device__ __forceinline__ bf16x8 coh_ld16(const unsigned short* p) {
  union { unsigned long long u[2]; bf16x8 v; } r;
  r.u[0] = __hip_atomic_load((const unsigned long long*)(const void*)p,
                             __ATOMIC_RELAXED, __HIP_MEMORY_SCOPE_AGENT);
  r.u[1] = __hip_atomic_load((const unsigned long long*)(const void*)(p + 4),
                             __ATOMIC_RELAXED, __HIP_MEMORY_SCOPE_AGENT);
  return r.v;
}

__device__ __forceinline__ void coh_st_h(unsigned short* p, unsigned short v) {
  asm volatile("global_store_short %0, %1, off sc1" ::"v"(p), "v"((unsigned int)v) : "memory");
}
__device__ __forceinline__ void coh_st_f(float* p, float v) {
  asm volatile("global_store_dword %0, %1, off sc1" ::"v"(p), "v"(v) : "memory");
}

// 8 consecutive f32 (cached load) -> bf16x8, RNE identical to f2bf store path.
__device__ __forceinline__ bf16x8 cvt8(const float* p) {
  f32x4 a = *(const f32x4*)p;
  f32x4 b = *(const f32x4*)(p + 4);
  union { unsigned short s[8]; bf16x8 v; } r;
#pragma unroll
  for (int j = 0; j < 4; j++) { r.s[j] = f2bf(a[j]); r.s[4 + j] = f2bf(b[j]); }
  return r.v;
}

// Pack weights: cell c (0=l0f,1=l0b,2=l1f,3=l1b), Wcat = [W_ih (K=512) | W_hh (K=256)],
// chunk (c, n16, kc): lane l holds W[n16*16 + (l&15)][kc*32 + (l>>4)*8 + j], j=0..7.
// chunk short-offset = ((c*64 + n16)*24 + kc)*512 + lane*8. n16 = gate*16 + hsl.
__global__ void wpack_kernel(const float* __restrict__ Wih0, const float* __restrict__ Whh0,
                             const float* __restrict__ bih0, const float* __restrict__ bhh0,
                             const float* __restrict__ Wih1, const float* __restrict__ Whh1,
                             const float* __restrict__ bih1, const float* __restrict__ bhh1,
                             unsigned short* __restrict__ wpack, float* __restrict__ bsum) {
  int tid = blockIdx.x * 256 + threadIdx.x;  // 4*64*24*64 = 393216 threads
  int lane = tid & 63;
  int chunk = tid >> 6;
  int kc = chunk % 24;
  int cn = chunk / 24;
  int n16 = cn & 63;
  int c = cn >> 6;
  int n = n16 * 16 + (lane & 15);
  int k0 = kc * 32 + (lane >> 4) * 8;
  const float* Wih = (c < 2) ? Wih0 : Wih1;
  const float* Whh = (c < 2) ? Whh0 : Whh1;
  int d = c & 1;
  unsigned short tmp[8];
#pragma unroll
  for (int j = 0; j < 8; j++) {
    int k = k0 + j;
    float val = (k < 512) ? Wih[(d * 1024 + n) * 512 + k]
                          : Whh[(d * 1024 + n) * 256 + (k - 512)];
    tmp[j] = f2bf(val);
  }
  *(u32x4*)(wpack + (size_t)tid * 8) = *(const u32x4*)tmp;
  if (tid < 4096) {
    int c2 = tid >> 10, n2 = tid & 1023;
    float b = (c2 < 2) ? (bih0[(c2 & 1) * 1024 + n2] + bhh0[(c2 & 1) * 1024 + n2])
                       : (bih1[(c2 & 1) * 1024 + n2] + bhh1[(c2 & 1) * 1024 + n2]);
    bsum[tid] = b;
  }
}

// init: h0 -> H slot 1 ([row][cell*256+hid] bf16), c0 -> C ([row][cell*256+hid] fp32)
// Also zero the barrier counters (each launch / graph replay).
__global__ void init_kernel(const float* __restrict__ code,
                            unsigned short* __restrict__ H1, float* __restrict__ C,
                            unsigned int* __restrict__ ctrs) {
  int t = blockIdx.x * 256 + threadIdx.x;  // 1M threads
  int row = t >> 10, col = t & 1023;
  H1[t] = f2bf(code[row * 2048 + col]);
  C[t] = code[row * 2048 + 1024 + col];
  if (blockIdx.x == 0 && threadIdx.x < 256) ctrs[threadIdx.x] = 0;
}

// Fence-free 32-block cluster barrier. All cross-block data is written with sc1
// (L3 point-of-coherence), so completion (vmcnt==0) == visibility. Monotonic
// counter (expect = 32*bar) avoids reset races. NO cache maintenance.
__device__ __forceinline__ void cl_barrier(unsigned int* c, unsigned int expect) {
  asm volatile("s_waitcnt vmcnt(0)" ::: "memory");  // incl. asm sc1 stores
  __syncthreads();
  if (threadIdx.x == 0) {
    __hip_atomic_fetch_add(c, 1u, __ATOMIC_RELAXED, __HIP_MEMORY_SCOPE_AGENT);
    while (__hip_atomic_load(c, __ATOMIC_RELAXED, __HIP_MEMORY_SCOPE_AGENT) < expect)
      __builtin_amdgcn_s_sleep(1);
  }
  __syncthreads();
}

// Persistent LSTM: block bx -> mb = bx&7 (128-row cluster), hsl = (bx>>3)&15,
// p = bx>>7. Owns cells {p (layer0), 2+p (layer1)} x hid [hsl*16,+16) x rows
// [mb*128,+128). 8 waves: stage-0 row-split (w*16), stage-1 (mh=w>>2, g1=w&3).
__global__ __launch_bounds__(512, 2) void lstm_persistent(
    const unsigned short* __restrict__ wpack, const float* __restrict__ bsum,
    const float* __restrict__ Cg, unsigned short* __restrict__ H0,
    unsigned short* __restrict__ H1, float* __restrict__ out,
    unsigned int* __restrict__ ctrs) {
  __shared__ unsigned short W0[96 * 512];   // 96 KB: layer-0 weights, resident
  __shared__ unsigned short A1s[32 * 768];  // 48 KB: stage-1 A quarter (swizzled)
  __shared__ float EX[32 * 65];             // 8.3 KB: stage-1 gate exchange

  const int bx = blockIdx.x;
  const int mb = bx & 7;
  const int hsl = (bx >> 3) & 15;
  const int p = bx >> 7;
  const int tid = threadIdx.x;
  const int lane = tid & 63;
  const int w = tid >> 6;
  const int q = lane >> 4;
  const int ln = lane & 15;
  const int g1 = w & 3;   // stage-1 wave gate
  const int mh = w >> 2;  // stage-1 wave m-half

  // --- layer-0 weights -> LDS once (96 x 1KB chunks, DMA)
#pragma unroll
  for (int i = 0; i < 12; i++) {
    int ci = w + i * 8;
    int gate = ci & 3, kc = ci >> 2;
    async_ld16(wpack + (size_t)(((p * 64 + gate * 16 + hsl) * 24 + kc)) * 512 + lane * 8,
               W0 + (size_t)ci * 512);
  }

  // --- layer-1 gate-g1 weights (regs; L2-warm if compiler rematerializes)
  bf16x8 wb1[24];
#pragma unroll
  for (int kc = 0; kc < 24; kc++)
    wb1[kc] = *(const bf16x8*)(
        wpack + (size_t)((((2 + p) * 64 + g1 * 16 + hsl) * 24 + kc)) * 512 + lane * 8);

  // --- biases, register-resident C-state
  const int colh = hsl * 16 + ln;
  float brg0[4];
#pragma unroll
  for (int g = 0; g < 4; g++) brg0[g] = bsum[p * 1024 + g * 256 + colh];
  const int ehid = tid & 15;
  const int erow = tid >> 4;
  const int colh1 = hsl * 16 + ehid;
  float brg1[4];
#pragma unroll
  for (int g = 0; g < 4; g++) brg1[g] = bsum[(2 + p) * 1024 + g * 256 + colh1];

  float c0r[4];
#pragma unroll
  for (int r = 0; r < 4; r++)
    c0r[r] = Cg[(size_t)(mb * 128 + w * 16 + q * 4 + r) * 1024 + p * 256 + colh];
  float c1r[4];
#pragma unroll
  for (int qq = 0; qq < 4; qq++)
    c1r[qq] = Cg[(size_t)(mb * 128 + qq * 32 + erow) * 1024 + (2 + p) * 256 + colh1];

  unsigned int* ctr = ctrs + mb * 32;  // one 128B line per cluster
  unsigned int bar = 0;
  const size_t ostride = (size_t)NSTEPS * 512;

  __syncthreads();  // W0 DMA drained (compiler emits vmcnt(0) before barrier)

  for (int t = 0; t < NSTEPS; t++) {
    const unsigned short* __restrict__ Hprev = (t & 1) ? H0 : H1;
    unsigned short* __restrict__ Hcur = (t & 1) ? H1 : H0;

    // ============ stage 0: layer 0, cell p ============
    f32x4 acc[4];
#pragma unroll
    for (int g = 0; g < 4; g++) acc[g] = (f32x4){0.f, 0.f, 0.f, 0.f};

    const int arowi = mb * 128 + w * 16 + ln;
    const size_t arow = (size_t)arowi * 1024 + q * 8;

    if (t > 0) {  // x-part = y(t-1) from out (write-once, cached; f2bf == old bits)
      const float* ob = out + (size_t)arowi * ostride + (size_t)(t - 1) * 512 + q * 8;
#pragma unroll
      for (int g = 0; g < 2; g++) {  // kc groups 0..7, 8..15
        bf16x8 fr[8];
#pragma unroll
        for (int kk = 0; kk < 8; kk++) fr[kk] = cvt8(ob + g * 256 + kk * 32);
#pragma unroll
        for (int kk = 0; kk < 8; kk++)
#pragma unroll
          for (int gt = 0; gt < 4; gt++) {
            bf16x8 bf = *(const bf16x8*)(W0 + (size_t)((g * 8 + kk) * 4 + gt) * 512 + lane * 8);
            acc[gt] = __builtin_amdgcn_mfma_f32_16x16x32_bf16(fr[kk], bf, acc[gt], 0, 0, 0);
          }
      }
    }
    {  // h-part = own h0(t-1): ping-pong buffer -> sc1 coherent loads
      const unsigned short* hb = Hprev + arow + p * 256;
      bf16x8 fr[8];
#pragma unroll
      for (int kk = 0; kk < 8; kk++) fr[kk] = coh_ld16(hb + kk * 32);
#pragma unroll
      for (int kk = 0; kk < 8; kk++)
#pragma unroll
        for (int gt = 0; gt < 4; gt++) {
          bf16x8 bf = *(const bf16x8*)(W0 + (size_t)((16 + kk) * 4 + gt) * 512 + lane * 8);
          acc[gt] = __builtin_amdgcn_mfma_f32_16x16x32_bf16(fr[kk], bf, acc[gt], 0, 0, 0);
        }
    }
#pragma unroll
    for (int r = 0; r < 4; r++) {
      int row = mb * 128 + w * 16 + q * 4 + r;
      float iv = sigm(acc[0][r] + brg0[0]);
      float fv = sigm(acc[1][r] + brg0[1]);
      float gv = tanh_f(acc[2][r] + brg0[2]);
      float ov = sigm(acc[3][r] + brg0[3]);
      float c2 = fv * c0r[r] + iv * gv;
      c0r[r] = c2;
      float hv = ov * tanh_f(c2);
      coh_st_h(Hcur + (size_t)row * 1024 + p * 256 + colh, f2bf(hv));
    }

    bar++;
    cl_barrier(ctr, 32u * bar);  // h0 visible (L3) to the cluster

    // ============ stage 1: layer 1, cell 2+p, 4x 32-row quarters ============
#pragma unroll
    for (int qq = 0; qq < 4; qq++) {
      // reg-stage 32 rows x 768 cols into A1s with XOR-swizzle (unit=16B bf16):
      // storage[row*96 + (k16 ^ (row&7))] = logical(row, k16).
#pragma unroll
      for (int rd = 0; rd < 6; rd++) {
        int u = rd * 512 + tid;
        int lrow = u / 96;
        int k16u = u % 96;
        int grow = mb * 128 + qq * 32 + lrow;
        bf16x8 val;
        if (k16u < 64) {  // x1 = h0 (this step): sc1 coherent
          val = coh_ld16(Hcur + (size_t)grow * 1024 + k16u * 8);
        } else if (t == 0) {  // own h1 init from H1 (init_kernel, flushed)
          val = coh_ld16(Hprev + (size_t)grow * 1024 + 512 + p * 256 + (k16u - 64) * 8);
        } else {  // own h1(t-1) = out slice t-1 (write-once, cached)
          val = cvt8(out + (size_t)grow * ostride + (size_t)(t - 1) * 512 + p * 256 +
                     (k16u - 64) * 8);
        }
        int sw = lrow * 96 + (k16u ^ (lrow & 7));
        *(bf16x8*)(A1s + (size_t)sw * 8) = val;
      }
      __syncthreads();

      // MFMA: wave (mh,g1): 16 rows x 16 cols (gate g1), K=768
      f32x4 a1acc = (f32x4){0.f, 0.f, 0.f, 0.f};
      const int lrow = mh * 16 + ln;
#pragma unroll
      for (int kc = 0; kc < 24; kc++) {
        int k16 = (kc * 4 + q) ^ (lrow & 7);
        bf16x8 af = *(const bf16x8*)(A1s + (size_t)(lrow * 96 + k16) * 8);
        a1acc = __builtin_amdgcn_mfma_f32_16x16x32_bf16(af, wb1[kc], a1acc, 0, 0, 0);
      }

#pragma unroll
      for (int r = 0; r < 4; r++)
        EX[(mh * 16 + q * 4 + r) * 65 + g1 * 16 + ln] = a1acc[r];
      __syncthreads();

      float gvs[4];
#pragma unroll
      for (int g = 0; g < 4; g++) gvs[g] = EX[erow * 65 + g * 16 + ehid] + brg1[g];
      float iv = sigm(gvs[0]);
      float fv = sigm(gvs[1]);
      float gg = tanh_f(gvs[2]);
      float ov = sigm(gvs[3]);
      float c2 = fv * c1r[qq] + iv * gg;
      c1r[qq] = c2;
      float hv = ov * tanh_f(c2);
      int grow = mb * 128 + qq * 32 + erow;
      // y goes ONLY to out, sc1 (write-once => safe for cached readers)
      coh_st_f(out + (size_t)grow * ostride + (size_t)t * 512 + p * 256 + colh1, hv);
    }

    if (t + 1 < NSTEPS) {
      bar++;
      cl_barrier(ctr, 32u * bar);  // out slice t + (nothing else) visible
    }
  }
}

extern "C" void kernel_launch(void* const* d_in, const int* in_sizes, int n_in,
                              void* d_out, int out_size, void* d_ws, size_t ws_size,
                              hipStream_t stream) {
  const float* code = (const float*)d_in[0];
  // d_in[1] = x  -- unused by the reference
  const float* Wih0 = (const float*)d_in[2];
  const float* Whh0 = (const float*)d_in[3];
  const float* bih0 = (const float*)d_in[4];
  const float* bhh0 = (const float*)d_in[5];
  const float* Wih1 = (const float*)d_in[6];
  const float* Whh1 = (const float*)d_in[7];
  const float* bih1 = (const float*)d_in[8];
  const float* bhh1 = (const float*)d_in[9];

  // d_ws layout (R3-compatible + 1KB barrier counters)
  unsigned short* wpack = (unsigned short*)d_ws;                        // 6,291,456 B
  float* bsum = (float*)((char*)d_ws + 6291456);                        // 16 KB
  float* C    = (float*)((char*)d_ws + 6291456 + 16384);                // 4 MB
  unsigned short* H0 = (unsigned short*)((char*)d_ws + 6291456 + 16384 + 4194304);  // 2 MB
  unsigned short* H1 = H0 + 1024 * 1024;                                // 2 MB
  unsigned int* ctrs = (unsigned int*)((char*)d_ws + 14696448);         // 1 KB

  float* out = (float*)d_out;

  wpack_kernel<<<1536, 256, 0, stream>>>(Wih0, Whh0, bih0, bhh0,
                                         Wih1, Whh1, bih1, bhh1, wpack, bsum);
  init_kernel<<<4096, 256, 0, stream>>>(code, H1, C, ctrs);
  lstm_persistent<<<256, 512, 0, stream>>>(wpack, bsum, C, H0, H1, out, ctrs);
}

// Round 4
// 1590.882 us; speedup vs baseline: 1.3796x; 1.3796x over previous
//
#include <hip/hip_runtime.h>
#include <hip/hip_bf16.h>

// SignalDecoder: 2-layer bidirectional LSTM, 52 steps, B=1024, HID=256.
// Round 7: persistent kernel with INTRA-XCD L2 coherence.
//   R4/R6 lesson: inter-XCD exchange (L3, sc1) costs ~40us/step (latency on a
//   serialized chain + 7x write-through amplification). Intra-XCD is the only
//   fast exchange: stores are write-through L1->L2; sc0 loads bypass stale L1
//   and hit the XCD's L2 (~200cy, 34TB/s). A 32-block cluster (mb = bx&7) on
//   ONE XCD needs zero cache maintenance.
//   The bx%8->XCD mapping is undefined, so we VERIFY it: each block reads
//   HW_REG_XCC_ID (m09-verified) and publishes it; a cluster that is not
//   XCD-homogeneous falls back to the sc1/L3 path (slow but correct, = R6).
//   Data flow/layout = verified R3: H[row][1024] bf16 (cols 0..511 h0 cells01,
//   cols 512..1023 y = h1 cells23), ping-pong H0/H1; C in registers all steps;
//   layer-0 W in LDS (96KB, loaded once); layer-1 W slice in regs. Loads are
//   batched asm global_load_dwordx4 blocks ending in vmcnt(0) (24 in flight).
//   FP order identical to R3 => absmax must be bit-identical.

#define NSTEPS 52

typedef __attribute__((ext_vector_type(8))) short bf16x8;
typedef __attribute__((ext_vector_type(4))) float f32x4;
typedef __attribute__((ext_vector_type(4))) unsigned int u32x4;

__device__ __forceinline__ unsigned short f2bf(float f) {
  union { float f; unsigned int u; } v; v.f = f;
  unsigned int r = v.u + 0x7fffu + ((v.u >> 16) & 1u);  // RNE
  return (unsigned short)(r >> 16);
}

__device__ __forceinline__ float sigm(float x) { return 1.f / (1.f + __expf(-x)); }
__device__ __forceinline__ float tanh_f(float x) { return 2.f / (1.f + __expf(-2.f * x)) - 1.f; }

__device__ __forceinline__ void async_ld16(const unsigned short* g, unsigned short* l) {
  __builtin_amdgcn_global_load_lds(
      (const __attribute__((address_space(1))) unsigned int*)g,
      (__attribute__((address_space(3))) unsigned int*)l, 16, 0, 0);
}

// ---- batched coherent loads: N loads in one asm block, vmcnt(0) at the end
// (outputs valid at asm exit -> no asm-output/waitcnt hazard). saddr form:
// base in SGPR pair, 32-bit byte voffset in VGPR, 13-bit imm offsets.
// Fast path: "sc0" (bypass L1, served by own-XCD L2).
// Slow path: "sc0 sc1" (bypass L1+L2, served by L3) - inter-XCD correct.

#define S0_LOADS(EX) asm volatile( \
  "global_load_dwordx4 %0, %24, %26 " EX "\n\t" \
  "global_load_dwordx4 %1, %24, %26 offset:64 " EX "\n\t" \
  "global_load_dwordx4 %2, %24, %26 offset:128 " EX "\n\t" \
  "global_load_dwordx4 %3, %24, %26 offset:192 " EX "\n\t" \
  "global_load_dwordx4 %4, %24, %26 offset:256 " EX "\n\t" \
  "global_load_dwordx4 %5, %24, %26 offset:320 " EX "\n\t" \
  "global_load_dwordx4 %6, %24, %26 offset:384 " EX "\n\t" \
  "global_load_dwordx4 %7, %24, %26 offset:448 " EX "\n\t" \
  "global_load_dwordx4 %8, %24, %26 offset:512 " EX "\n\t" \
  "global_load_dwordx4 %9, %24, %26 offset:576 " EX "\n\t" \
  "global_load_dwordx4 %10, %24, %26 offset:640 " EX "\n\t" \
  "global_load_dwordx4 %11, %24, %26 offset:704 " EX "\n\t" \
  "global_load_dwordx4 %12, %24, %26 offset:768 " EX "\n\t" \
  "global_load_dwordx4 %13, %24, %26 offset:832 " EX "\n\t" \
  "global_load_dwordx4 %14, %24, %26 offset:896 " EX "\n\t" \
  "global_load_dwordx4 %15, %24, %26 offset:960 " EX "\n\t" \
  "global_load_dwordx4 %16, %25, %26 " EX "\n\t" \
  "global_load_dwordx4 %17, %25, %26 offset:64 " EX "\n\t" \
  "global_load_dwordx4 %18, %25, %26 offset:128 " EX "\n\t" \
  "global_load_dwordx4 %19, %25, %26 offset:192 " EX "\n\t" \
  "global_load_dwordx4 %20, %25, %26 offset:256 " EX "\n\t" \
  "global_load_dwordx4 %21, %25, %26 offset:320 " EX "\n\t" \
  "global_load_dwordx4 %22, %25, %26 offset:384 " EX "\n\t" \
  "global_load_dwordx4 %23, %25, %26 offset:448 " EX "\n\t" \
  "s_waitcnt vmcnt(0)" \
  : "=&v"(o[0]), "=&v"(o[1]), "=&v"(o[2]), "=&v"(o[3]), "=&v"(o[4]), "=&v"(o[5]), \
    "=&v"(o[6]), "=&v"(o[7]), "=&v"(o[8]), "=&v"(o[9]), "=&v"(o[10]), "=&v"(o[11]), \
    "=&v"(o[12]), "=&v"(o[13]), "=&v"(o[14]), "=&v"(o[15]), "=&v"(o[16]), "=&v"(o[17]), \
    "=&v"(o[18]), "=&v"(o[19]), "=&v"(o[20]), "=&v"(o[21]), "=&v"(o[22]), "=&v"(o[23]) \
  : "v"(vx), "v"(vh), "s"(hb) : "memory")

#define S0_LOADS8(EX) asm volatile( \
  "global_load_dwordx4 %0, %8, %9 " EX "\n\t" \
  "global_load_dwordx4 %1, %8, %9 offset:64 " EX "\n\t" \
  "global_load_dwordx4 %2, %8, %9 offset:128 " EX "\n\t" \
  "global_load_dwordx4 %3, %8, %9 offset:192 " EX "\n\t" \
  "global_load_dwordx4 %4, %8, %9 offset:256 " EX "\n\t" \
  "global_load_dwordx4 %5, %8, %9 offset:320 " EX "\n\t" \
  "global_load_dwordx4 %6, %8, %9 offset:384 " EX "\n\t" \
  "global_load_dwordx4 %7, %8, %9 offset:448 " EX "\n\t" \
  "s_waitcnt vmcnt(0)" \
  : "=&v"(o[16]), "=&v"(o[17]), "=&v"(o[18]), "=&v"(o[19]), "=&v"(o[20]), \
    "=&v"(o[21]), "=&v"(o[22]), "=&v"(o[23]) \
  : "v"(vh), "s"(hb) : "memory")

#define S1_LOADS(EX) asm volatile( \
  "global_load_dwordx4 %0, %6, %12 " EX "\n\t" \
  "global_load_dwordx4 %1, %7, %12 " EX "\n\t" \
  "global_load_dwordx4 %2, %8, %12 " EX "\n\t" \
  "global_load_dwordx4 %3, %9, %12 " EX "\n\t" \
  "global_load_dwordx4 %4, %10, %12 " EX "\n\t" \
  "global_load_dwordx4 %5, %11, %12 " EX "\n\t" \
  "s_waitcnt vmcnt(0)" \
  : "=&v"(o6[0]), "=&v"(o6[1]), "=&v"(o6[2]), "=&v"(o6[3]), "=&v"(o6[4]), "=&v"(o6[5]) \
  : "v"(vs[0]), "v"(vs[1]), "v"(vs[2]), "v"(vs[3]), "v"(vs[4]), "v"(vs[5]), "s"(hb) \
  : "memory")

template <bool SLOW>
__device__ __forceinline__ void st2(unsigned short* p, unsigned short v) {
  if constexpr (SLOW)
    asm volatile("global_store_short %0, %1, off sc0 sc1" ::"v"(p), "v"((unsigned int)v) : "memory");
  else
    asm volatile("global_store_short %0, %1, off sc0" ::"v"(p), "v"((unsigned int)v) : "memory");
}

// Pack weights: cell c (0=l0f,1=l0b,2=l1f,3=l1b), Wcat = [W_ih (K=512) | W_hh (K=256)],
// chunk (c, n16, kc): lane l holds W[n16*16 + (l&15)][kc*32 + (l>>4)*8 + j], j=0..7.
// chunk short-offset = ((c*64 + n16)*24 + kc)*512 + lane*8. n16 = gate*16 + hsl.
__global__ void wpack_kernel(const float* __restrict__ Wih0, const float* __restrict__ Whh0,
                             const float* __restrict__ bih0, const float* __restrict__ bhh0,
                             const float* __restrict__ Wih1, const float* __restrict__ Whh1,
                             const float* __restrict__ bih1, const float* __restrict__ bhh1,
                             unsigned short* __restrict__ wpack, float* __restrict__ bsum) {
  int tid = blockIdx.x * 256 + threadIdx.x;  // 393216 threads
  int lane = tid & 63;
  int chunk = tid >> 6;
  int kc = chunk % 24;
  int cn = chunk / 24;
  int n16 = cn & 63;
  int c = cn >> 6;
  int n = n16 * 16 + (lane & 15);
  int k0 = kc * 32 + (lane >> 4) * 8;
  const float* Wih = (c < 2) ? Wih0 : Wih1;
  const float* Whh = (c < 2) ? Whh0 : Whh1;
  int d = c & 1;
  unsigned short tmp[8];
#pragma unroll
  for (int j = 0; j < 8; j++) {
    int k = k0 + j;
    float val = (k < 512) ? Wih[(d * 1024 + n) * 512 + k]
                          : Whh[(d * 1024 + n) * 256 + (k - 512)];
    tmp[j] = f2bf(val);
  }
  *(u32x4*)(wpack + (size_t)tid * 8) = *(const u32x4*)tmp;
  if (tid < 4096) {
    int c2 = tid >> 10, n2 = tid & 1023;
    float b = (c2 < 2) ? (bih0[(c2 & 1) * 1024 + n2] + bhh0[(c2 & 1) * 1024 + n2])
                       : (bih1[(c2 & 1) * 1024 + n2] + bhh1[(c2 & 1) * 1024 + n2]);
    bsum[tid] = b;
  }
}

// init: h -> H1 ([row][cell*256+hid] bf16, cells 0..3: cols 512.. are init y),
// c -> C fp32. Zero 512 barrier/xcc words (re-zeroed every graph replay).
__global__ void init_kernel(const float* __restrict__ code,
                            unsigned short* __restrict__ H1, float* __restrict__ C,
                            unsigned int* __restrict__ ctrs) {
  int t = blockIdx.x * 256 + threadIdx.x;  // 1M threads
  int row = t >> 10, col = t & 1023;
  H1[t] = f2bf(code[row * 2048 + col]);
  C[t] = code[row * 2048 + 1024 + col];
  if (blockIdx.x == 0 && threadIdx.x < 256) {
    ctrs[threadIdx.x] = 0;
    ctrs[threadIdx.x + 256] = 0;
  }
}

// 32-block cluster barrier: vmcnt drain (stores visible at their scope's
// coherence point: L2 fast / L3 slow) + monotonic agent atomic counter.
__device__ __forceinline__ void cl_barrier(unsigned int* c, unsigned int expect) {
  asm volatile("s_waitcnt vmcnt(0)" ::: "memory");
  __syncthreads();
  if (threadIdx.x == 0) {
    __hip_atomic_fetch_add(c, 1u, __ATOMIC_RELAXED, __HIP_MEMORY_SCOPE_AGENT);
    while (__hip_atomic_load(c, __ATOMIC_RELAXED, __HIP_MEMORY_SCOPE_AGENT) < expect)
      __builtin_amdgcn_s_sleep(1);
  }
  __syncthreads();
}

// The 52-step decoder loop. SLOW=false: cluster is XCD-homogeneous, exchange
// through own-XCD L2 (sc0). SLOW=true: exchange through L3 (sc0 sc1).
template <bool SLOW>
__device__ __forceinline__ void run_decoder(
    const unsigned short* __restrict__ wpack, const float* __restrict__ bsum,
    const float* __restrict__ Cg, unsigned short* __restrict__ H0,
    float* __restrict__ out, unsigned int* ctr,
    unsigned short* W0, unsigned short* A1s, float* EX, int bx) {
  const int mb = bx & 7;
  const int hsl = (bx >> 3) & 15;
  const int p = bx >> 7;
  const int tid = threadIdx.x;
  const int lane = tid & 63;
  const int w = tid >> 6;
  const int q = lane >> 4;
  const int ln = lane & 15;
  const int g1 = w & 3;   // stage-1 wave gate
  const int mh = w >> 2;  // stage-1 wave m-half (within 32-row quarter)

  // --- layer-1 gate-g1 weight slice (regs; re-fills from L1/L2 if spilled)
  bf16x8 wb1[24];
#pragma unroll
  for (int kc = 0; kc < 24; kc++)
    wb1[kc] = *(const bf16x8*)(
        wpack + (size_t)((((2 + p) * 64 + g1 * 16 + hsl) * 24 + kc)) * 512 + lane * 8);

  // --- biases, register-resident C-state
  const int colh = hsl * 16 + ln;
  float brg0[4];
#pragma unroll
  for (int g = 0; g < 4; g++) brg0[g] = bsum[p * 1024 + g * 256 + colh];
  const int ehid = tid & 15;
  const int erow = tid >> 4;
  const int colh1 = hsl * 16 + ehid;
  float brg1[4];
#pragma unroll
  for (int g = 0; g < 4; g++) brg1[g] = bsum[(2 + p) * 1024 + g * 256 + colh1];

  float c0r[4];
#pragma unroll
  for (int r = 0; r < 4; r++)
    c0r[r] = Cg[(size_t)(mb * 128 + w * 16 + q * 4 + r) * 1024 + p * 256 + colh];
  float c1r[4];
#pragma unroll
  for (int qq = 0; qq < 4; qq++)
    c1r[qq] = Cg[(size_t)(mb * 128 + qq * 32 + erow) * 1024 + (2 + p) * 256 + colh1];

  // --- step-invariant address material. H base = H0; H1 = H0 + 2MB; parity
  // selects via bit 21 of the byte voffset. Row stride 2048 B (1024 bf16).
  const unsigned short* hb = H0;  // saddr for all batched loads
  const int arowi = mb * 128 + w * 16 + ln;
  const unsigned int vx_rel = (unsigned)(arowi * 2048 + 1024 + q * 16);       // y(t-1) cols
  const unsigned int vh_rel = (unsigned)(arowi * 2048 + p * 512 + q * 16);    // own h0 cols
  // stage-1 staging: unit u = rd*512+tid of quarter qq: lrow=u/96, k16u=u%96;
  // k16u<64 -> h0 (Hcur); else -> y(t-1) (Hprev). LDS XOR-swizzled dest.
  unsigned int s1rel[6], s1ym[6];
  unsigned short* s1lds[6];
#pragma unroll
  for (int rd = 0; rd < 6; rd++) {
    int u = rd * 512 + tid;
    int lrow = u / 96;
    int k16u = u % 96;
    int isY = (k16u >= 64);
    s1rel[rd] = (unsigned)((mb * 128 + lrow) * 2048 +
                           (isY ? (1024 + p * 512 + (k16u - 64) * 16) : (k16u * 16)));
    s1ym[rd] = isY ? 0x200000u : 0u;
    s1lds[rd] = A1s + (size_t)(lrow * 96 + (k16u ^ (lrow & 7))) * 8;
  }

  unsigned int bar = 1;  // bar 1 consumed by the xcc-check barrier
  const size_t ostride = (size_t)NSTEPS * 512;

  for (int t = 0; t < NSTEPS; t++) {
    const unsigned int p1 = (unsigned)(t & 1);
    const unsigned int p1M = p1 << 21;          // Hcur in H1?
    const unsigned int selP = (p1 ^ 1u) << 21;  // Hprev in H1?
    unsigned short* __restrict__ Hcur = H0 + (p1 ? 1048576 : 0);

    // ============ stage 0: layer 0, cell p ============
    u32x4 o[24];
    {
      const unsigned int vx = vx_rel + selP;
      const unsigned int vh = vh_rel + selP;
      if (t > 0) {
        if constexpr (SLOW) S0_LOADS("sc0 sc1"); else S0_LOADS("sc0");
      } else {
        if constexpr (SLOW) S0_LOADS8("sc0 sc1"); else S0_LOADS8("sc0");
      }
    }

    f32x4 acc[4];
#pragma unroll
    for (int g = 0; g < 4; g++) acc[g] = (f32x4){0.f, 0.f, 0.f, 0.f};

    if (t > 0) {
#pragma unroll
      for (int kc = 0; kc < 16; kc++) {
#pragma unroll
        for (int gt = 0; gt < 4; gt++) {
          bf16x8 bf = *(const bf16x8*)(W0 + (size_t)(kc * 4 + gt) * 512 + lane * 8);
          acc[gt] = __builtin_amdgcn_mfma_f32_16x16x32_bf16(
              __builtin_bit_cast(bf16x8, o[kc]), bf, acc[gt], 0, 0, 0);
        }
      }
    }
#pragma unroll
    for (int kc = 16; kc < 24; kc++) {
#pragma unroll
      for (int gt = 0; gt < 4; gt++) {
        bf16x8 bf = *(const bf16x8*)(W0 + (size_t)(kc * 4 + gt) * 512 + lane * 8);
        acc[gt] = __builtin_amdgcn_mfma_f32_16x16x32_bf16(
            __builtin_bit_cast(bf16x8, o[kc]), bf, acc[gt], 0, 0, 0);
      }
    }

#pragma unroll
    for (int r = 0; r < 4; r++) {
      int row = mb * 128 + w * 16 + q * 4 + r;
      float iv = sigm(acc[0][r] + brg0[0]);
      float fv = sigm(acc[1][r] + brg0[1]);
      float gv = tanh_f(acc[2][r] + brg0[2]);
      float ov = sigm(acc[3][r] + brg0[3]);
      float c2 = fv * c0r[r] + iv * gv;
      c0r[r] = c2;
      float hv = ov * tanh_f(c2);
      st2<SLOW>(Hcur + (size_t)row * 1024 + p * 256 + colh, f2bf(hv));
    }

    bar++;
    cl_barrier(ctr, 32u * bar);  // h0(t) visible to the cluster

    // ============ stage 1: layer 1, cell 2+p, 4x 32-row quarters ============
#pragma unroll
    for (int qq = 0; qq < 4; qq++) {
      unsigned int vs[6];
#pragma unroll
      for (int rd = 0; rd < 6; rd++)
        vs[rd] = s1rel[rd] + (unsigned)(qq * 65536) + (p1M ^ s1ym[rd]);
      u32x4 o6[6];
      if constexpr (SLOW) S1_LOADS("sc0 sc1"); else S1_LOADS("sc0");
#pragma unroll
      for (int rd = 0; rd < 6; rd++)
        *(bf16x8*)(s1lds[rd]) = __builtin_bit_cast(bf16x8, o6[rd]);
      __syncthreads();

      // MFMA: wave (mh,g1): 16 rows x 16 cols (gate g1), K=768
      f32x4 a1acc = (f32x4){0.f, 0.f, 0.f, 0.f};
      const int lrow = mh * 16 + ln;
#pragma unroll
      for (int kc = 0; kc < 24; kc++) {
        int k16 = (kc * 4 + q) ^ (lrow & 7);
        bf16x8 af = *(const bf16x8*)(A1s + (size_t)(lrow * 96 + k16) * 8);
        a1acc = __builtin_amdgcn_mfma_f32_16x16x32_bf16(af, wb1[kc], a1acc, 0, 0, 0);
      }

#pragma unroll
      for (int r = 0; r < 4; r++)
        EX[(mh * 16 + q * 4 + r) * 65 + g1 * 16 + ln] = a1acc[r];
      __syncthreads();

      float gvs[4];
#pragma unroll
      for (int g = 0; g < 4; g++) gvs[g] = EX[erow * 65 + g * 16 + ehid] + brg1[g];
      float iv = sigm(gvs[0]);
      float fv = sigm(gvs[1]);
      float gg = tanh_f(gvs[2]);
      float ov = sigm(gvs[3]);
      float c2 = fv * c1r[qq] + iv * gg;
      c1r[qq] = c2;
      float hv = ov * tanh_f(c2);
      int grow = mb * 128 + qq * 32 + erow;
      st2<SLOW>(Hcur + (size_t)grow * 1024 + 512 + p * 256 + colh1, f2bf(hv));
      out[(size_t)grow * ostride + (size_t)t * 512 + p * 256 + colh1] = hv;  // write-only
    }

    if (t + 1 < NSTEPS) {
      bar++;
      cl_barrier(ctr, 32u * bar);  // y(t) visible before next step's stage 0
    }
  }
}

__global__ __launch_bounds__(512, 2) void lstm_persistent(
    const unsigned short* __restrict__ wpack, const float* __restrict__ bsum,
    const float* __restrict__ Cg, unsigned short* __restrict__ H0,
    float* __restrict__ out, unsigned int* __restrict__ ctrs) {
  __shared__ unsigned short W0[96 * 512];   // 96 KB layer-0 weights, resident
  __shared__ unsigned short A1s[32 * 768];  // 48 KB stage-1 A quarter (swizzled)
  __shared__ float EX[32 * 65];             // 8.3 KB gate exchange
  __shared__ int hs;

  const int bx = blockIdx.x;
  const int mb = bx & 7;
  const int hsl = (bx >> 3) & 15;
  const int p = bx >> 7;
  const int tid = threadIdx.x;
  const int lane = tid & 63;
  const int w = tid >> 6;

  // layer-0 weights -> LDS once (96 x 1KB chunks, DMA); drained by 1st barrier
#pragma unroll
  for (int i = 0; i < 12; i++) {
    int ci = w + i * 8;
    int gate = ci & 3, kc = ci >> 2;
    async_ld16(wpack + (size_t)(((p * 64 + gate * 16 + hsl) * 24 + kc)) * 512 + lane * 8,
               W0 + (size_t)ci * 512);
  }

  // --- XCD-homogeneity check for this 32-block cluster (correctness gate for
  // the L2 fast path; G16: never ASSUME the dispatch mapping).
  unsigned int xcc = 0;
  asm volatile("s_getreg_b32 %0, hwreg(HW_REG_XCC_ID)" : "=s"(xcc));
  unsigned int* xarr = ctrs + 256;
  unsigned int* ctr = ctrs + mb * 32;
  if (tid == 0)
    __hip_atomic_store(xarr + bx, xcc + 1u, __ATOMIC_RELAXED, __HIP_MEMORY_SCOPE_AGENT);
  cl_barrier(ctr, 32u);  // bar = 1 (also drains the W0 DMA)
  if (tid == 0) {
    int h = 1;
    for (int j = 0; j < 32; j++) {
      unsigned int v =
          __hip_atomic_load(xarr + mb + j * 8, __ATOMIC_RELAXED, __HIP_MEMORY_SCOPE_AGENT);
      h &= (v == xcc + 1u);
    }
    hs = h;
  }
  __syncthreads();

  if (hs)
    run_decoder<false>(wpack, bsum, Cg, H0, out, ctr, W0, A1s, EX, bx);
  else
    run_decoder<true>(wpack, bsum, Cg, H0, out, ctr, W0, A1s, EX, bx);
}

extern "C" void kernel_launch(void* const* d_in, const int* in_sizes, int n_in,
                              void* d_out, int out_size, void* d_ws, size_t ws_size,
                              hipStream_t stream) {
  const float* code = (const float*)d_in[0];
  // d_in[1] = x  -- unused by the reference
  const float* Wih0 = (const float*)d_in[2];
  const float* Whh0 = (const float*)d_in[3];
  const float* bih0 = (const float*)d_in[4];
  const float* bhh0 = (const float*)d_in[5];
  const float* Wih1 = (const float*)d_in[6];
  const float* Whh1 = (const float*)d_in[7];
  const float* bih1 = (const float*)d_in[8];
  const float* bhh1 = (const float*)d_in[9];

  // d_ws layout
  unsigned short* wpack = (unsigned short*)d_ws;                        // 6,291,456 B
  float* bsum = (float*)((char*)d_ws + 6291456);                        // 16 KB
  float* C    = (float*)((char*)d_ws + 6307840);                        // 4 MB
  unsigned short* H0 = (unsigned short*)((char*)d_ws + 10502144);       // 2 MB
  unsigned short* H1 = H0 + 1048576;                                    // 2 MB (contiguous)
  unsigned int* ctrs = (unsigned int*)((char*)d_ws + 14696448);         // 2 KB (ctr + xcc)

  float* out = (float*)d_out;

  wpack_kernel<<<1536, 256, 0, stream>>>(Wih0, Whh0, bih0, bhh0,
                                         Wih1, Whh1, bih1, bhh1, wpack, bsum);
  init_kernel<<<4096, 256, 0, stream>>>(code, H1, C, ctrs);
  lstm_persistent<<<256, 512, 0, stream>>>(wpack, bsum, C, H0, out, ctrs);
}